// Round 7
// baseline (808.391 us; speedup 1.0000x reference)
//
#include <hip/hip_runtime.h>

using u16 = unsigned short;
using u32 = unsigned int;

typedef __bf16 v8bf __attribute__((ext_vector_type(8)));
typedef float  v4f  __attribute__((ext_vector_type(4)));

#define ST  68    // u16 stride for agg stage rows (34 dwords: odd -> conflict-free columns)
#define STK 132   // u16 stride for 128-wide bf16 LDS rows
#define EPB 128   // edges per block in agg_k
#define T2S 34    // u16 stride of transposed ew tile rows (17 dwords, odd -> conflict-free)

// 1-instruction RNE f32->bf16 (identical rounding to manual round-to-nearest-even)
__device__ __forceinline__ u32 cvtpk(float lo, float hi){
  u32 r; asm("v_cvt_pk_bf16_f32 %0, %1, %2" : "=v"(r) : "v"(lo), "v"(hi)); return r;
}
__device__ __forceinline__ u16 f2b(float f){ return (u16)cvtpk(f, f); }
__device__ __forceinline__ float b2f(u16 b){
  u32 u = ((u32)b) << 16;
  return __builtin_bit_cast(float, u);
}

union bfu { v8bf v; u16 s[8]; u32 w[4]; };

__device__ __forceinline__ v8bf zero8(){
  bfu u;
  #pragma unroll
  for (int i = 0; i < 4; i++) u.w[i] = 0;
  return u.v;
}

// ---------------- one-time weight prep: bf16 images, pre-strided / identity-folded ----------------
// wimg:  [0..2048) = W1 image [64 rows][32 k] (k<8 real, else 0)
//        [2048..2048+64*ST) = W2 image [64 out][ST] (c<64 real, else 0)
// wiimg: dense [64][128] bf16 of Wi
// wlimg: 3 x dense [64][128] bf16 of (Wl + [I|0])
__global__ __launch_bounds__(256) void prep_k(const float* __restrict__ W1, const float* __restrict__ W2,
                                              const float* __restrict__ Wi, const float* __restrict__ Wl,
                                              u16* __restrict__ wimg, u16* __restrict__ wiimg,
                                              u16* __restrict__ wlimg){
  int i = blockIdx.x*256 + threadIdx.x;
  if (i < 2048){ int r = i >> 5, k = i & 31; wimg[i] = (k < 8) ? f2b(W1[r*8+k]) : (u16)0; }
  if (i < 64*ST){ int o = i / ST, c = i % ST; wimg[2048+i] = (c < 64) ? f2b(W2[o*64+c]) : (u16)0; }
  if (i < 8192) wiimg[i] = f2b(Wi[i]);
  if (i < 3*8192){
    int oc = i & 8191, o = oc >> 7, c = oc & 127;
    wlimg[i] = f2b(Wl[i] + ((c == o) ? 1.f : 0.f));
  }
}

// ---------------- counting sort by target ----------------

__global__ __launch_bounds__(256) void hist_k(const int* __restrict__ col, int* __restrict__ counts, int E){
  int e = blockIdx.x*256 + threadIdx.x;
  if (e < E) atomicAdd(&counts[col[e]], 1);
}

__global__ __launch_bounds__(1024) void scan1_k(const int* __restrict__ counts, int* __restrict__ start,
                                                int* __restrict__ bsum, int N){
  __shared__ int s[1024];
  int tid = threadIdx.x;
  int i = blockIdx.x*1024 + tid;
  int v = (i < N) ? counts[i] : 0;
  s[tid] = v; __syncthreads();
  for (int off = 1; off < 1024; off <<= 1){
    int t = (tid >= off) ? s[tid-off] : 0;
    __syncthreads();
    s[tid] += t;
    __syncthreads();
  }
  if (i < N) start[i] = s[tid] - v;
  if (tid == 1023) bsum[blockIdx.x] = s[1023];
}

__global__ __launch_bounds__(1024) void scan2_k(int* __restrict__ bsum, int nb, int* __restrict__ start,
                                                int N, int E){
  __shared__ int s[1024];
  int tid = threadIdx.x;
  int v = (tid < nb) ? bsum[tid] : 0;
  s[tid] = v; __syncthreads();
  for (int off = 1; off < 1024; off <<= 1){
    int t = (tid >= off) ? s[tid-off] : 0;
    __syncthreads();
    s[tid] += t;
    __syncthreads();
  }
  if (tid < nb) bsum[tid] = s[tid] - v;
  if (tid == 0) start[N] = E;
}

__global__ __launch_bounds__(1024) void scan3_k(int* __restrict__ start, const int* __restrict__ bsum,
                                                int* __restrict__ cursor, int N){
  int i = blockIdx.x*1024 + threadIdx.x;
  if (i < N){
    int v = start[i] + bsum[blockIdx.x];
    start[i] = v;
    cursor[i] = v;
  }
}

// minimal scatter: only the 4B permutation index goes to a random slot
__global__ __launch_bounds__(256) void scatp_k(const int* __restrict__ col, int* __restrict__ cursor,
                                               int* __restrict__ perm, int E){
  int e0 = (blockIdx.x*256 + threadIdx.x)*4;
  if (e0 + 3 < E){
    int4 c4 = *(const int4*)(col + e0);
    int cs[4] = {c4.x, c4.y, c4.z, c4.w};
    #pragma unroll
    for (int i = 0; i < 4; i++){
      int p = atomicAdd(&cursor[cs[i]], 1);
      perm[p] = e0 + i;
    }
  } else {
    for (int i = 0; i < 4; i++){
      int e = e0 + i; if (e >= E) break;
      int p = atomicAdd(&cursor[col[e]], 1);
      perm[p] = e;
    }
  }
}

// streaming build: sequential positions, L3-resident gathers, fully coalesced SoA writes
__global__ __launch_bounds__(256) void build_k(const int* __restrict__ perm, const int* __restrict__ row,
                                               const int* __restrict__ col, const float* __restrict__ ea,
                                               u32* __restrict__ eas, int2* __restrict__ rp, int E){
  int p0 = (blockIdx.x*256 + threadIdx.x)*4;
  if (p0 + 3 < E){
    int4 e4 = *(const int4*)(perm + p0);
    int es[4] = {e4.x, e4.y, e4.z, e4.w};
    #pragma unroll
    for (int i = 0; i < 4; i++){
      int e = es[i];
      const float4* eap = (const float4*)(ea + (size_t)e*8);
      float4 a0 = eap[0], a1 = eap[1];
      ((int4*)eas)[p0+i] = make_int4((int)cvtpk(a0.x, a0.y), (int)cvtpk(a0.z, a0.w),
                                     (int)cvtpk(a1.x, a1.y), (int)cvtpk(a1.z, a1.w));
      rp[p0+i] = make_int2(row[e], col[e]);
    }
  } else {
    for (int i = 0; i < 4; i++){
      int p = p0 + i; if (p >= E) break;
      int e = perm[p];
      const float4* eap = (const float4*)(ea + (size_t)e*8);
      float4 a0 = eap[0], a1 = eap[1];
      ((int4*)eas)[p] = make_int4((int)cvtpk(a0.x, a0.y), (int)cvtpk(a0.z, a0.w),
                                  (int)cvtpk(a1.x, a1.y), (int)cvtpk(a1.z, a1.w));
      rp[p] = make_int2(row[e], col[e]);
    }
  }
}

// ---------------- fused edge-MLP (both layers MFMA) + segmented aggregation ----------------
// layer2 computes ew TRANSPOSED (D[ch][edge]) so the scan reads channel rows contiguously.

template<int MODE>   // 0: degree (xv=1)   1: layer (gather V bf16)
__global__ __launch_bounds__(256) void agg_k(const u32* __restrict__ eas, const int2* __restrict__ rp,
                                             const u16* __restrict__ wimg,
                                             const u16* __restrict__ V, float* __restrict__ U, int E){
  __shared__ __align__(16) u16 stage[EPB*ST];   // ea -> t1 -> (overlay) t2 [64ch][T2S] per wave
  __shared__ __align__(16) u16 w2s[64*ST];
  __shared__ __align__(16) u16 w1s[64*32];
  __shared__ int sl[EPB], tl[EPB];
  int tid = threadIdx.x;
  int j0 = blockIdx.x*EPB;

  if (tid < EPB){
    int j = j0 + tid;
    int4 a = make_int4(0,0,0,0); int2 c = make_int2(0,0);
    if (j < E){
      a = ((const int4*)eas)[j];
      c = rp[j];
    }
    sl[tid] = c.x;
    tl[tid] = c.y;
    *(int2*)&stage[tid*ST]     = make_int2(a.x, a.y);
    *(int2*)&stage[tid*ST + 4] = make_int2(a.z, a.w);
  }
  {
    // stage pre-converted weight images: plain vector copies, no converts.
    // w1s = 2048 u16 = 256 uint4; w2s = 4352 u16 = 544 uint4 (uint4 = 8 u16).
    const uint4* src = (const uint4*)wimg;
    uint4* d1 = (uint4*)w1s;
    uint4* d2 = (uint4*)w2s;
    if (tid < 256) d1[tid] = src[tid];
    for (int i = tid; i < 544; i += 256) d2[i] = src[256 + i];
  }
  __syncthreads();

  int w = tid >> 6, lane = tid & 63;
  int m16 = lane & 15, quad = lane >> 4;
  int base = w*32;

  // ---- layer 1 via MFMA (K padded 8->32; quads 1-3 zero), D[edge][ch] -> t1 in stage ----
  v8bf af1[2];
  #pragma unroll
  for (int mi = 0; mi < 2; mi++){
    af1[mi] = zero8();
    if (quad == 0){
      int rr = base + mi*16 + m16;
      int2 p0 = *(const int2*)&stage[rr*ST];
      int2 p1 = *(const int2*)&stage[rr*ST + 4];
      bfu u; u.w[0] = (u32)p0.x; u.w[1] = (u32)p0.y; u.w[2] = (u32)p1.x; u.w[3] = (u32)p1.y;
      af1[mi] = u.v;
    }
  }
  v4f acc1[2][4];
  #pragma unroll
  for (int mi = 0; mi < 2; mi++)
    #pragma unroll
    for (int ni = 0; ni < 4; ni++) acc1[mi][ni] = (v4f){0.f,0.f,0.f,0.f};
  #pragma unroll
  for (int ni = 0; ni < 4; ni++){
    v8bf bf = *(const v8bf*)&w1s[(ni*16 + m16)*32 + quad*8];
    #pragma unroll
    for (int mi = 0; mi < 2; mi++)
      acc1[mi][ni] = __builtin_amdgcn_mfma_f32_16x16x32_bf16(af1[mi], bf, acc1[mi][ni], 0, 0, 0);
  }
  #pragma unroll
  for (int mi = 0; mi < 2; mi++)
    #pragma unroll
    for (int ni = 0; ni < 4; ni++)
      #pragma unroll
      for (int r = 0; r < 4; r++)
        stage[(base + mi*16 + quad*4 + r)*ST + ni*16 + m16] = f2b(fmaxf(acc1[mi][ni][r], 0.f));

  // ---- layer 2 swapped: D[ch][edge] = W2 x t1^T ----
  // B-frags (t1 rows, contiguous) read BEFORE the t2 overlay writes the same region.
  v8bf bfr[2][2];
  #pragma unroll
  for (int ni = 0; ni < 2; ni++)
    #pragma unroll
    for (int ks = 0; ks < 2; ks++)
      bfr[ni][ks] = *(const v8bf*)&stage[(base + ni*16 + m16)*ST + ks*32 + quad*8];
  v4f acc2[4][2];
  #pragma unroll
  for (int mi = 0; mi < 4; mi++)
    #pragma unroll
    for (int ni = 0; ni < 2; ni++) acc2[mi][ni] = (v4f){0.f,0.f,0.f,0.f};
  #pragma unroll
  for (int ks = 0; ks < 2; ks++)
    #pragma unroll
    for (int mi = 0; mi < 4; mi++){
      v8bf afr = *(const v8bf*)&w2s[(mi*16 + m16)*ST + ks*32 + quad*8];
      #pragma unroll
      for (int ni = 0; ni < 2; ni++)
        acc2[mi][ni] = __builtin_amdgcn_mfma_f32_16x16x32_bf16(afr, bfr[ni][ks], acc2[mi][ni], 0, 0, 0);
    }
  // t2 tile overlays this wave's stage region: [64 ch][T2S] u16 at offset base*ST (2176 u16 exactly)
  int t2b = base*ST;
  #pragma unroll
  for (int mi = 0; mi < 4; mi++)
    #pragma unroll
    for (int ni = 0; ni < 2; ni++)
      #pragma unroll
      for (int r = 0; r < 4; r++)
        stage[t2b + (mi*16 + quad*4 + r)*T2S + ni*16 + m16] = f2b(fmaxf(acc2[mi][ni][r], 0.f));

  // ---- segmented scan over this wave's 32 sorted edges; lane = channel ----
  int lim = E - (j0 + base); if (lim > 32) lim = 32;
  const u32* t2w = (const u32*)&stage[t2b + lane*T2S];
  if (lim == 32){
    int tv = tl[base + (lane & 31)];
    int sv = sl[base + (lane & 31)];
    int tvp = __shfl_up(tv, 1, 32);
    unsigned long long bal = __ballot((lane & 31) != 0 && tv != tvp);
    u32 m = (u32)bal;                       // segment-start mask, bit q = boundary before edge q
    u32 ew[16];
    #pragma unroll
    for (int i = 0; i < 16; i++) ew[i] = t2w[i];
    float s = 0.f;
    int cur = __builtin_amdgcn_readlane(tv, 0);
    #pragma unroll
    for (int q0 = 0; q0 < 32; q0 += 8){
      float xv[8];
      #pragma unroll
      for (int qi = 0; qi < 8; qi++){
        if (MODE){
          int src = __builtin_amdgcn_readlane(sv, q0 + qi);
          xv[qi] = b2f(V[(size_t)src*64 + lane]);
        } else xv[qi] = 1.f;
      }
      #pragma unroll
      for (int qi = 0; qi < 8; qi++){
        int q = q0 + qi;
        if (m & (1u << q)){
          atomicAdd(&U[(size_t)cur*64 + lane], s); s = 0.f;
          cur = __builtin_amdgcn_readlane(tv, q);
        }
        u32 wb = ew[q >> 1];
        u32 bits = (q & 1) ? (wb & 0xffff0000u) : (wb << 16);
        s += __builtin_bit_cast(float, bits) * xv[qi];
      }
    }
    atomicAdd(&U[(size_t)cur*64 + lane], s);
  } else if (lim > 0){
    float s = 0.f;
    int cur = tl[base];
    for (int q = 0; q < lim; q++){
      float wv = b2f(stage[t2b + lane*T2S + q]);
      float xvv = MODE ? b2f(V[(size_t)sl[base+q]*64 + lane]) : 1.f;
      int t = tl[base+q];
      if (t != cur){ atomicAdd(&U[(size_t)cur*64 + lane], s); s = 0.f; cur = t; }
      s += wv*xvv;
    }
    atomicAdd(&U[(size_t)cur*64 + lane], s);
  }
}

__global__ __launch_bounds__(256) void degfin_k(float* __restrict__ U, float* __restrict__ dinv, int NH){
  int i = blockIdx.x*256 + threadIdx.x;
  if (i < NH){
    dinv[i] = rsqrtf(1.f + U[i]);
    U[i] = 0.f;
  }
}

// ---------------- xlin via MFMA: 64 nodes/block; xlin stored bf16 ----------------

__global__ __launch_bounds__(256) void xlin_k(const float* __restrict__ x, const u16* __restrict__ wiimg,
                                              const float* __restrict__ bi, const float* __restrict__ wconv0,
                                              const float* __restrict__ dinv,
                                              u16* __restrict__ xlin, u16* __restrict__ V, int N){
  __shared__ __align__(16) u16 wb[64*STK];   // Wi bf16 [o][k]
  __shared__ __align__(16) u16 as[64*STK];   // x  bf16 [node][k]
  int tid = threadIdx.x;
  // wb copy: 8192 u16 = 2048 uint2 (uint2 = 4 u16; rows 8B-aligned at stride STK)
  for (int i = tid; i < 2048; i += 256){ int o = i >> 5, c = i & 31; *(uint2*)&wb[o*STK + c*4] = ((const uint2*)wiimg)[i]; }
  int nb0 = blockIdx.x*64;
  // x staging: pair-convert via cvt_pk, store u32
  for (int i = tid; i < 4096; i += 256){
    int nn = i >> 6, k2 = i & 63; int n = nb0 + nn;
    u32 v = 0;
    if (n < N){ float2 xx = *(const float2*)&x[(size_t)n*128 + k2*2]; v = cvtpk(xx.x, xx.y); }
    *(u32*)&as[nn*STK + k2*2] = v;
  }
  __syncthreads();
  int w = tid >> 6, lane = tid & 63;
  int m16 = lane & 15, quad = lane >> 4;
  int wbase = w*16;
  v8bf af[4];
  #pragma unroll
  for (int ks = 0; ks < 4; ks++) af[ks] = *(const v8bf*)&as[(wbase+m16)*STK + ks*32 + quad*8];
  v4f acc[4];
  #pragma unroll
  for (int ni = 0; ni < 4; ni++) acc[ni] = (v4f){0.f,0.f,0.f,0.f};
  #pragma unroll
  for (int ks = 0; ks < 4; ks++){
    #pragma unroll
    for (int ni = 0; ni < 4; ni++){
      v8bf bf = *(const v8bf*)&wb[(ni*16+m16)*STK + ks*32 + quad*8];
      acc[ni] = __builtin_amdgcn_mfma_f32_16x16x32_bf16(af[ks], bf, acc[ni], 0, 0, 0);
    }
  }
  #pragma unroll
  for (int ni = 0; ni < 4; ni++){
    int c = ni*16 + m16;
    float wc = wconv0[c], bc = bi[c];
    #pragma unroll
    for (int r = 0; r < 4; r++){
      int n = nb0 + wbase + quad*4 + r;
      if (n < N){
        float val = acc[ni][r] + bc;
        size_t idx = (size_t)n*64 + c;
        xlin[idx] = f2b(val);
        V[idx] = f2b(fmaxf(val, 0.f) * wc * dinv[idx]);
      }
    }
  }
}

// ---------------- epilogue via MFMA: residual folded as identity in Wl (prep'd) ----------------

__global__ __launch_bounds__(256) void epi_k(const u16* __restrict__ xlin, const float* __restrict__ dinv,
                                             float* __restrict__ U, u16* __restrict__ V,
                                             const u16* __restrict__ wlimg, const float* __restrict__ bconv,
                                             const float* __restrict__ wconv_next, const float* __restrict__ Wo,
                                             float* __restrict__ out, int N, int last){
  __shared__ __align__(16) u16 wb[64*STK];   // (Wl + [I|0]) bf16 [o][c]
  __shared__ __align__(16) u16 an[64*STK];   // concat(x_, g) bf16 [node][c]
  int tid = threadIdx.x;
  for (int i = tid; i < 2048; i += 256){ int o = i >> 5, c = i & 31; *(uint2*)&wb[o*STK + c*4] = ((const uint2*)wlimg)[i]; }
  int nb0 = blockIdx.x*64;
  for (int i = tid; i < 4096; i += 256){
    int nn = i >> 6, c = i & 63; int n = nb0 + nn;
    u16 xb = 0, gb = 0;
    if (n < N){
      size_t idx = (size_t)n*64 + c;
      xb = xlin[idx];
      float g = dinv[idx]*(b2f(V[idx]) + U[idx]) + bconv[c];
      gb = f2b(g);
      if (!last) U[idx] = 0.f;
    }
    an[nn*STK + c] = xb;
    an[nn*STK + 64 + c] = gb;
  }
  __syncthreads();
  int w = tid >> 6, lane = tid & 63;
  int m16 = lane & 15, quad = lane >> 4;
  int wbase = w*16;
  v8bf af[4];
  #pragma unroll
  for (int ks = 0; ks < 4; ks++) af[ks] = *(const v8bf*)&an[(wbase+m16)*STK + ks*32 + quad*8];
  v4f acc[4];
  #pragma unroll
  for (int ni = 0; ni < 4; ni++) acc[ni] = (v4f){0.f,0.f,0.f,0.f};
  #pragma unroll
  for (int ks = 0; ks < 4; ks++){
    #pragma unroll
    for (int ni = 0; ni < 4; ni++){
      v8bf bf = *(const v8bf*)&wb[(ni*16+m16)*STK + ks*32 + quad*8];
      acc[ni] = __builtin_amdgcn_mfma_f32_16x16x32_bf16(af[ks], bf, acc[ni], 0, 0, 0);
    }
  }
  if (!last){
    #pragma unroll
    for (int ni = 0; ni < 4; ni++){
      int c = ni*16 + m16;
      float wc = wconv_next[c];
      #pragma unroll
      for (int r = 0; r < 4; r++){
        int n = nb0 + wbase + quad*4 + r;
        if (n < N){
          size_t idx = (size_t)n*64 + c;
          V[idx] = f2b(fmaxf(acc[ni][r], 0.f) * wc * dinv[idx]);
        }
      }
    }
  } else {
    float part[4];
    #pragma unroll
    for (int r = 0; r < 4; r++){
      float p = 0.f;
      int rowl = wbase + quad*4 + r;
      #pragma unroll
      for (int ni = 0; ni < 4; ni++){
        int c = ni*16 + m16;
        float xl = b2f(an[rowl*STK + c]);
        float hr = fmaxf(acc[ni][r], 0.f);
        p += xl*Wo[c] + hr*Wo[64 + c];
      }
      part[r] = p;
    }
    #pragma unroll
    for (int off = 1; off < 16; off <<= 1)
      #pragma unroll
      for (int r = 0; r < 4; r++) part[r] += __shfl_xor(part[r], off, 64);
    if (m16 == 0){
      #pragma unroll
      for (int r = 0; r < 4; r++){
        int n = nb0 + wbase + quad*4 + r;
        if (n < N) out[n] = part[r];
      }
    }
  }
}

extern "C" void kernel_launch(void* const* d_in, const int* in_sizes, int n_in,
                              void* d_out, int out_size, void* d_ws, size_t ws_size,
                              hipStream_t stream){
  const float* x     = (const float*)d_in[0];
  const int*   ei    = (const int*)  d_in[1];
  const float* ea    = (const float*)d_in[2];
  const float* W1    = (const float*)d_in[3];
  const float* W2    = (const float*)d_in[4];
  const float* Wi    = (const float*)d_in[5];
  const float* bi    = (const float*)d_in[6];
  const float* wconv = (const float*)d_in[7];
  const float* bconv = (const float*)d_in[8];
  const float* Wl    = (const float*)d_in[9];
  const float* Wo    = (const float*)d_in[10];
  float* out = (float*)d_out;

  int N = in_sizes[0] / 128;
  int E = in_sizes[2] / 8;
  const int* row = ei;
  const int* col = ei + E;

  char* p = (char*)d_ws;
  auto alloc = [&](size_t nbytes){ char* r = p; p += (nbytes + 255) & ~(size_t)255; return r; };

  int*   counts = (int*)  alloc((size_t)N*4);
  int*   start  = (int*)  alloc((size_t)(N+1)*4);
  int*   cursor = (int*)  alloc((size_t)N*4);
  int*   bsum   = (int*)  alloc(4096);
  u32*   eas    = (u32*)  alloc((size_t)E*16);
  int2*  rp     = (int2*) alloc((size_t)E*8);
  int*   perm   = (int*)  alloc((size_t)E*4);
  float* U      = (float*)alloc((size_t)N*256);
  float* dinv   = (float*)alloc((size_t)N*256);
  u16*   xlin   = (u16*)  alloc((size_t)N*128);
  u16*   V      = (u16*)  alloc((size_t)N*128);
  u16*   wimg   = (u16*)  alloc((size_t)(2048 + 64*ST)*2);
  u16*   wiimg  = (u16*)  alloc((size_t)8192*2);
  u16*   wlimg  = (u16*)  alloc((size_t)3*8192*2);

  int gE   = (E + 255) / 256;
  int gE4  = (E + 1023) / 1024;
  int gA   = (E + EPB - 1) / EPB;
  int nb1  = (N + 1023) / 1024;
  int gN64 = (N + 63) / 64;
  int gNH  = (N*64 + 255) / 256;

  hipMemsetAsync(counts, 0, (size_t)N*4, stream);
  hipMemsetAsync(U, 0, (size_t)N*256, stream);

  prep_k <<<96, 256, 0, stream>>>(W1, W2, Wi, Wl, wimg, wiimg, wlimg);
  hist_k <<<gE, 256, 0, stream>>>(col, counts, E);
  scan1_k<<<nb1, 1024, 0, stream>>>(counts, start, bsum, N);
  scan2_k<<<1, 1024, 0, stream>>>(bsum, nb1, start, N, E);
  scan3_k<<<nb1, 1024, 0, stream>>>(start, bsum, cursor, N);
  scatp_k<<<gE4, 256, 0, stream>>>(col, cursor, perm, E);
  build_k<<<gE4, 256, 0, stream>>>(perm, row, col, ea, eas, rp, E);

  agg_k<0><<<gA, 256, 0, stream>>>(eas, rp, wimg, V, U, E);   // degree
  degfin_k<<<gNH, 256, 0, stream>>>(U, dinv, N*64);
  xlin_k  <<<gN64, 256, 0, stream>>>(x, wiimg, bi, wconv, dinv, xlin, V, N);

  agg_k<1><<<gA, 256, 0, stream>>>(eas, rp, wimg, V, U, E);
  epi_k   <<<gN64, 256, 0, stream>>>(xlin, dinv, U, V, wlimg + 0*8192, bconv +   0, wconv +  64, Wo, out, N, 0);
  agg_k<1><<<gA, 256, 0, stream>>>(eas, rp, wimg, V, U, E);
  epi_k   <<<gN64, 256, 0, stream>>>(xlin, dinv, U, V, wlimg + 1*8192, bconv +  64, wconv + 128, Wo, out, N, 0);
  agg_k<1><<<gA, 256, 0, stream>>>(eas, rp, wimg, V, U, E);
  epi_k   <<<gN64, 256, 0, stream>>>(xlin, dinv, U, V, wlimg + 2*8192, bconv + 128, wconv      , Wo, out, N, 1);
}

// Round 8
// 667.549 us; speedup vs baseline: 1.2110x; 1.2110x over previous
//
#include <hip/hip_runtime.h>

using u16 = unsigned short;
using u32 = unsigned int;

typedef __bf16 v8bf __attribute__((ext_vector_type(8)));
typedef float  v4f  __attribute__((ext_vector_type(4)));

#define ST  68    // u16 stride for agg stage rows (34 dwords: odd -> conflict-free columns)
#define STK 132   // u16 stride for 128-wide bf16 LDS rows
#define EPB 128   // edges per block in agg_k
#define T2S 34    // u16 stride of transposed ew tile rows (17 dwords, odd -> conflict-free)
#define RW2 8     // record width in u32: [0..3]=ea bf16x8, [4]=src, [5]=tgt, [6..7]=pad (32B aligned)

// 1-instruction RNE f32->bf16 (identical rounding to manual round-to-nearest-even)
__device__ __forceinline__ u32 cvtpk(float lo, float hi){
  u32 r; asm("v_cvt_pk_bf16_f32 %0, %1, %2" : "=v"(r) : "v"(lo), "v"(hi)); return r;
}
__device__ __forceinline__ u16 f2b(float f){ return (u16)cvtpk(f, f); }
__device__ __forceinline__ float b2f(u16 b){
  u32 u = ((u32)b) << 16;
  return __builtin_bit_cast(float, u);
}

union bfu { v8bf v; u16 s[8]; u32 w[4]; };

__device__ __forceinline__ v8bf zero8(){
  bfu u;
  #pragma unroll
  for (int i = 0; i < 4; i++) u.w[i] = 0;
  return u.v;
}

// ---------------- one-time weight prep: bf16 images, pre-strided / identity-folded ----------------
// wimg:  [0..2048) = W1 image [64 rows][32 k] (k<8 real, else 0)
//        [2048..2048+64*ST) = W2 image [64 out][ST] (c<64 real, else 0)
// wiimg: dense [64][128] bf16 of Wi
// wlimg: 3 x dense [64][128] bf16 of (Wl + [I|0])
__global__ __launch_bounds__(256) void prep_k(const float* __restrict__ W1, const float* __restrict__ W2,
                                              const float* __restrict__ Wi, const float* __restrict__ Wl,
                                              u16* __restrict__ wimg, u16* __restrict__ wiimg,
                                              u16* __restrict__ wlimg){
  int i = blockIdx.x*256 + threadIdx.x;
  if (i < 2048){ int r = i >> 5, k = i & 31; wimg[i] = (k < 8) ? f2b(W1[r*8+k]) : (u16)0; }
  if (i < 64*ST){ int o = i / ST, c = i % ST; wimg[2048+i] = (c < 64) ? f2b(W2[o*64+c]) : (u16)0; }
  if (i < 8192) wiimg[i] = f2b(Wi[i]);
  if (i < 3*8192){
    int oc = i & 8191, o = oc >> 7, c = oc & 127;
    wlimg[i] = f2b(Wl[i] + ((c == o) ? 1.f : 0.f));
  }
}

// ---------------- counting sort by target ----------------

// hist + rank in one pass: the atomic's return value IS the within-bucket rank.
__global__ __launch_bounds__(256) void histr_k(const int* __restrict__ col, int* __restrict__ counts,
                                               int* __restrict__ rank, int E){
  int e = blockIdx.x*256 + threadIdx.x;
  if (e < E) rank[e] = atomicAdd(&counts[col[e]], 1);
}

__global__ __launch_bounds__(1024) void scan1_k(const int* __restrict__ counts, int* __restrict__ start,
                                                int* __restrict__ bsum, int N){
  __shared__ int s[1024];
  int tid = threadIdx.x;
  int i = blockIdx.x*1024 + tid;
  int v = (i < N) ? counts[i] : 0;
  s[tid] = v; __syncthreads();
  for (int off = 1; off < 1024; off <<= 1){
    int t = (tid >= off) ? s[tid-off] : 0;
    __syncthreads();
    s[tid] += t;
    __syncthreads();
  }
  if (i < N) start[i] = s[tid] - v;
  if (tid == 1023) bsum[blockIdx.x] = s[1023];
}

__global__ __launch_bounds__(1024) void scan2_k(int* __restrict__ bsum, int nb, int* __restrict__ start,
                                                int N, int E){
  __shared__ int s[1024];
  int tid = threadIdx.x;
  int v = (tid < nb) ? bsum[tid] : 0;
  s[tid] = v; __syncthreads();
  for (int off = 1; off < 1024; off <<= 1){
    int t = (tid >= off) ? s[tid-off] : 0;
    __syncthreads();
    s[tid] += t;
    __syncthreads();
  }
  if (tid < nb) bsum[tid] = s[tid] - v;
  if (tid == 0) start[N] = E;
}

__global__ __launch_bounds__(1024) void scan3_k(int* __restrict__ start, const int* __restrict__ bsum, int N){
  int i = blockIdx.x*1024 + threadIdx.x;
  if (i < N) start[i] += bsum[blockIdx.x];
}

// minimal-scatter build: all reads coalesced at e; one hot gather (start[col]);
// ONE 32B-aligned record store per edge = exactly one random line-touch, no atomics.
__global__ __launch_bounds__(256) void build2_k(const int* __restrict__ rank, const int* __restrict__ start,
                                                const int* __restrict__ row, const int* __restrict__ col,
                                                const float* __restrict__ ea, u32* __restrict__ rec, int E){
  int e = blockIdx.x*256 + threadIdx.x;
  if (e < E){
    int c = col[e];
    int p = start[c] + rank[e];
    const float4* eap = (const float4*)(ea + (size_t)e*8);
    float4 a0 = eap[0], a1 = eap[1];
    int4* r4 = (int4*)(rec + (size_t)p*RW2);
    r4[0] = make_int4((int)cvtpk(a0.x, a0.y), (int)cvtpk(a0.z, a0.w),
                      (int)cvtpk(a1.x, a1.y), (int)cvtpk(a1.z, a1.w));
    r4[1] = make_int4(row[e], c, 0, 0);
  }
}

// ---------------- fused edge-MLP (both layers MFMA) + segmented aggregation ----------------
// layer2 computes ew TRANSPOSED (D[ch][edge]) so the scan reads channel rows contiguously.

template<int MODE>   // 0: degree (xv=1)   1: layer (gather V bf16)
__global__ __launch_bounds__(256) void agg_k(const u32* __restrict__ rec, const u16* __restrict__ wimg,
                                             const u16* __restrict__ V, float* __restrict__ U, int E){
  __shared__ __align__(16) u16 stage[EPB*ST];   // ea -> t1 -> (overlay) t2 [64ch][T2S] per wave
  __shared__ __align__(16) u16 w2s[64*ST];
  __shared__ __align__(16) u16 w1s[64*32];
  __shared__ int sl[EPB], tl[EPB];
  int tid = threadIdx.x;
  int j0 = blockIdx.x*EPB;

  if (tid < EPB){
    int j = j0 + tid;
    int4 a = make_int4(0,0,0,0), b = make_int4(0,0,0,0);
    if (j < E){
      const int4* r4 = (const int4*)(rec + (size_t)j*RW2);
      a = r4[0]; b = r4[1];
    }
    sl[tid] = b.x;
    tl[tid] = b.y;
    *(int2*)&stage[tid*ST]     = make_int2(a.x, a.y);
    *(int2*)&stage[tid*ST + 4] = make_int2(a.z, a.w);
  }
  {
    // stage pre-converted weight images: plain vector copies, no converts.
    // w1s = 2048 u16 = 256 uint4; w2s = 4352 u16 = 544 uint4 (uint4 = 8 u16).
    const uint4* src = (const uint4*)wimg;
    uint4* d1 = (uint4*)w1s;
    uint4* d2 = (uint4*)w2s;
    if (tid < 256) d1[tid] = src[tid];
    for (int i = tid; i < 544; i += 256) d2[i] = src[256 + i];
  }
  __syncthreads();

  int w = tid >> 6, lane = tid & 63;
  int m16 = lane & 15, quad = lane >> 4;
  int base = w*32;

  // ---- layer 1 via MFMA (K padded 8->32; quads 1-3 zero), D[edge][ch] -> t1 in stage ----
  v8bf af1[2];
  #pragma unroll
  for (int mi = 0; mi < 2; mi++){
    af1[mi] = zero8();
    if (quad == 0){
      int rr = base + mi*16 + m16;
      int2 p0 = *(const int2*)&stage[rr*ST];
      int2 p1 = *(const int2*)&stage[rr*ST + 4];
      bfu u; u.w[0] = (u32)p0.x; u.w[1] = (u32)p0.y; u.w[2] = (u32)p1.x; u.w[3] = (u32)p1.y;
      af1[mi] = u.v;
    }
  }
  v4f acc1[2][4];
  #pragma unroll
  for (int mi = 0; mi < 2; mi++)
    #pragma unroll
    for (int ni = 0; ni < 4; ni++) acc1[mi][ni] = (v4f){0.f,0.f,0.f,0.f};
  #pragma unroll
  for (int ni = 0; ni < 4; ni++){
    v8bf bf = *(const v8bf*)&w1s[(ni*16 + m16)*32 + quad*8];
    #pragma unroll
    for (int mi = 0; mi < 2; mi++)
      acc1[mi][ni] = __builtin_amdgcn_mfma_f32_16x16x32_bf16(af1[mi], bf, acc1[mi][ni], 0, 0, 0);
  }
  #pragma unroll
  for (int mi = 0; mi < 2; mi++)
    #pragma unroll
    for (int ni = 0; ni < 4; ni++)
      #pragma unroll
      for (int r = 0; r < 4; r++)
        stage[(base + mi*16 + quad*4 + r)*ST + ni*16 + m16] = f2b(fmaxf(acc1[mi][ni][r], 0.f));

  // ---- layer 2 swapped: D[ch][edge] = W2 x t1^T ----
  // B-frags (t1 rows, contiguous) read BEFORE the t2 overlay writes the same region.
  v8bf bfr[2][2];
  #pragma unroll
  for (int ni = 0; ni < 2; ni++)
    #pragma unroll
    for (int ks = 0; ks < 2; ks++)
      bfr[ni][ks] = *(const v8bf*)&stage[(base + ni*16 + m16)*ST + ks*32 + quad*8];
  v4f acc2[4][2];
  #pragma unroll
  for (int mi = 0; mi < 4; mi++)
    #pragma unroll
    for (int ni = 0; ni < 2; ni++) acc2[mi][ni] = (v4f){0.f,0.f,0.f,0.f};
  #pragma unroll
  for (int ks = 0; ks < 2; ks++)
    #pragma unroll
    for (int mi = 0; mi < 4; mi++){
      v8bf afr = *(const v8bf*)&w2s[(mi*16 + m16)*ST + ks*32 + quad*8];
      #pragma unroll
      for (int ni = 0; ni < 2; ni++)
        acc2[mi][ni] = __builtin_amdgcn_mfma_f32_16x16x32_bf16(afr, bfr[ni][ks], acc2[mi][ni], 0, 0, 0);
    }
  // t2 tile overlays this wave's stage region: [64 ch][T2S] u16 at offset base*ST (2176 u16 exactly)
  int t2b = base*ST;
  #pragma unroll
  for (int mi = 0; mi < 4; mi++)
    #pragma unroll
    for (int ni = 0; ni < 2; ni++)
      #pragma unroll
      for (int r = 0; r < 4; r++)
        stage[t2b + (mi*16 + quad*4 + r)*T2S + ni*16 + m16] = f2b(fmaxf(acc2[mi][ni][r], 0.f));

  // ---- segmented scan over this wave's 32 sorted edges; lane = channel ----
  int lim = E - (j0 + base); if (lim > 32) lim = 32;
  const u32* t2w = (const u32*)&stage[t2b + lane*T2S];
  if (lim == 32){
    int tv = tl[base + (lane & 31)];
    int sv = sl[base + (lane & 31)];
    int tvp = __shfl_up(tv, 1, 32);
    unsigned long long bal = __ballot((lane & 31) != 0 && tv != tvp);
    u32 m = (u32)bal;                       // segment-start mask, bit q = boundary before edge q
    u32 ew[16];
    #pragma unroll
    for (int i = 0; i < 16; i++) ew[i] = t2w[i];
    float s = 0.f;
    int cur = __builtin_amdgcn_readlane(tv, 0);
    #pragma unroll
    for (int q0 = 0; q0 < 32; q0 += 8){
      float xv[8];
      #pragma unroll
      for (int qi = 0; qi < 8; qi++){
        if (MODE){
          int src = __builtin_amdgcn_readlane(sv, q0 + qi);
          xv[qi] = b2f(V[(size_t)src*64 + lane]);
        } else xv[qi] = 1.f;
      }
      #pragma unroll
      for (int qi = 0; qi < 8; qi++){
        int q = q0 + qi;
        if (m & (1u << q)){
          atomicAdd(&U[(size_t)cur*64 + lane], s); s = 0.f;
          cur = __builtin_amdgcn_readlane(tv, q);
        }
        u32 wb = ew[q >> 1];
        u32 bits = (q & 1) ? (wb & 0xffff0000u) : (wb << 16);
        s += __builtin_bit_cast(float, bits) * xv[qi];
      }
    }
    atomicAdd(&U[(size_t)cur*64 + lane], s);
  } else if (lim > 0){
    float s = 0.f;
    int cur = tl[base];
    for (int q = 0; q < lim; q++){
      float wv = b2f(stage[t2b + lane*T2S + q]);
      float xvv = MODE ? b2f(V[(size_t)sl[base+q]*64 + lane]) : 1.f;
      int t = tl[base+q];
      if (t != cur){ atomicAdd(&U[(size_t)cur*64 + lane], s); s = 0.f; cur = t; }
      s += wv*xvv;
    }
    atomicAdd(&U[(size_t)cur*64 + lane], s);
  }
}

__global__ __launch_bounds__(256) void degfin_k(float* __restrict__ U, float* __restrict__ dinv, int NH){
  int i = blockIdx.x*256 + threadIdx.x;
  if (i < NH){
    dinv[i] = rsqrtf(1.f + U[i]);
    U[i] = 0.f;
  }
}

// ---------------- xlin via MFMA: 64 nodes/block; xlin stored bf16 ----------------

__global__ __launch_bounds__(256) void xlin_k(const float* __restrict__ x, const u16* __restrict__ wiimg,
                                              const float* __restrict__ bi, const float* __restrict__ wconv0,
                                              const float* __restrict__ dinv,
                                              u16* __restrict__ xlin, u16* __restrict__ V, int N){
  __shared__ __align__(16) u16 wb[64*STK];   // Wi bf16 [o][k]
  __shared__ __align__(16) u16 as[64*STK];   // x  bf16 [node][k]
  int tid = threadIdx.x;
  // wb copy: 8192 u16 = 2048 uint2 (uint2 = 4 u16; rows 8B-aligned at stride STK)
  for (int i = tid; i < 2048; i += 256){ int o = i >> 5, c = i & 31; *(uint2*)&wb[o*STK + c*4] = ((const uint2*)wiimg)[i]; }
  int nb0 = blockIdx.x*64;
  // x staging: pair-convert via cvt_pk, store u32
  for (int i = tid; i < 4096; i += 256){
    int nn = i >> 6, k2 = i & 63; int n = nb0 + nn;
    u32 v = 0;
    if (n < N){ float2 xx = *(const float2*)&x[(size_t)n*128 + k2*2]; v = cvtpk(xx.x, xx.y); }
    *(u32*)&as[nn*STK + k2*2] = v;
  }
  __syncthreads();
  int w = tid >> 6, lane = tid & 63;
  int m16 = lane & 15, quad = lane >> 4;
  int wbase = w*16;
  v8bf af[4];
  #pragma unroll
  for (int ks = 0; ks < 4; ks++) af[ks] = *(const v8bf*)&as[(wbase+m16)*STK + ks*32 + quad*8];
  v4f acc[4];
  #pragma unroll
  for (int ni = 0; ni < 4; ni++) acc[ni] = (v4f){0.f,0.f,0.f,0.f};
  #pragma unroll
  for (int ks = 0; ks < 4; ks++){
    #pragma unroll
    for (int ni = 0; ni < 4; ni++){
      v8bf bf = *(const v8bf*)&wb[(ni*16+m16)*STK + ks*32 + quad*8];
      acc[ni] = __builtin_amdgcn_mfma_f32_16x16x32_bf16(af[ks], bf, acc[ni], 0, 0, 0);
    }
  }
  #pragma unroll
  for (int ni = 0; ni < 4; ni++){
    int c = ni*16 + m16;
    float wc = wconv0[c], bc = bi[c];
    #pragma unroll
    for (int r = 0; r < 4; r++){
      int n = nb0 + wbase + quad*4 + r;
      if (n < N){
        float val = acc[ni][r] + bc;
        size_t idx = (size_t)n*64 + c;
        xlin[idx] = f2b(val);
        V[idx] = f2b(fmaxf(val, 0.f) * wc * dinv[idx]);
      }
    }
  }
}

// ---------------- epilogue via MFMA: residual folded as identity in Wl (prep'd) ----------------

__global__ __launch_bounds__(256) void epi_k(const u16* __restrict__ xlin, const float* __restrict__ dinv,
                                             float* __restrict__ U, u16* __restrict__ V,
                                             const u16* __restrict__ wlimg, const float* __restrict__ bconv,
                                             const float* __restrict__ wconv_next, const float* __restrict__ Wo,
                                             float* __restrict__ out, int N, int last){
  __shared__ __align__(16) u16 wb[64*STK];   // (Wl + [I|0]) bf16 [o][c]
  __shared__ __align__(16) u16 an[64*STK];   // concat(x_, g) bf16 [node][c]
  int tid = threadIdx.x;
  for (int i = tid; i < 2048; i += 256){ int o = i >> 5, c = i & 31; *(uint2*)&wb[o*STK + c*4] = ((const uint2*)wlimg)[i]; }
  int nb0 = blockIdx.x*64;
  for (int i = tid; i < 4096; i += 256){
    int nn = i >> 6, c = i & 63; int n = nb0 + nn;
    u16 xb = 0, gb = 0;
    if (n < N){
      size_t idx = (size_t)n*64 + c;
      xb = xlin[idx];
      float g = dinv[idx]*(b2f(V[idx]) + U[idx]) + bconv[c];
      gb = f2b(g);
      if (!last) U[idx] = 0.f;
    }
    an[nn*STK + c] = xb;
    an[nn*STK + 64 + c] = gb;
  }
  __syncthreads();
  int w = tid >> 6, lane = tid & 63;
  int m16 = lane & 15, quad = lane >> 4;
  int wbase = w*16;
  v8bf af[4];
  #pragma unroll
  for (int ks = 0; ks < 4; ks++) af[ks] = *(const v8bf*)&an[(wbase+m16)*STK + ks*32 + quad*8];
  v4f acc[4];
  #pragma unroll
  for (int ni = 0; ni < 4; ni++) acc[ni] = (v4f){0.f,0.f,0.f,0.f};
  #pragma unroll
  for (int ks = 0; ks < 4; ks++){
    #pragma unroll
    for (int ni = 0; ni < 4; ni++){
      v8bf bf = *(const v8bf*)&wb[(ni*16+m16)*STK + ks*32 + quad*8];
      acc[ni] = __builtin_amdgcn_mfma_f32_16x16x32_bf16(af[ks], bf, acc[ni], 0, 0, 0);
    }
  }
  if (!last){
    #pragma unroll
    for (int ni = 0; ni < 4; ni++){
      int c = ni*16 + m16;
      float wc = wconv_next[c];
      #pragma unroll
      for (int r = 0; r < 4; r++){
        int n = nb0 + wbase + quad*4 + r;
        if (n < N){
          size_t idx = (size_t)n*64 + c;
          V[idx] = f2b(fmaxf(acc[ni][r], 0.f) * wc * dinv[idx]);
        }
      }
    }
  } else {
    float part[4];
    #pragma unroll
    for (int r = 0; r < 4; r++){
      float p = 0.f;
      int rowl = wbase + quad*4 + r;
      #pragma unroll
      for (int ni = 0; ni < 4; ni++){
        int c = ni*16 + m16;
        float xl = b2f(an[rowl*STK + c]);
        float hr = fmaxf(acc[ni][r], 0.f);
        p += xl*Wo[c] + hr*Wo[64 + c];
      }
      part[r] = p;
    }
    #pragma unroll
    for (int off = 1; off < 16; off <<= 1)
      #pragma unroll
      for (int r = 0; r < 4; r++) part[r] += __shfl_xor(part[r], off, 64);
    if (m16 == 0){
      #pragma unroll
      for (int r = 0; r < 4; r++){
        int n = nb0 + wbase + quad*4 + r;
        if (n < N) out[n] = part[r];
      }
    }
  }
}

extern "C" void kernel_launch(void* const* d_in, const int* in_sizes, int n_in,
                              void* d_out, int out_size, void* d_ws, size_t ws_size,
                              hipStream_t stream){
  const float* x     = (const float*)d_in[0];
  const int*   ei    = (const int*)  d_in[1];
  const float* ea    = (const float*)d_in[2];
  const float* W1    = (const float*)d_in[3];
  const float* W2    = (const float*)d_in[4];
  const float* Wi    = (const float*)d_in[5];
  const float* bi    = (const float*)d_in[6];
  const float* wconv = (const float*)d_in[7];
  const float* bconv = (const float*)d_in[8];
  const float* Wl    = (const float*)d_in[9];
  const float* Wo    = (const float*)d_in[10];
  float* out = (float*)d_out;

  int N = in_sizes[0] / 128;
  int E = in_sizes[2] / 8;
  const int* row = ei;
  const int* col = ei + E;

  char* p = (char*)d_ws;
  auto alloc = [&](size_t nbytes){ char* r = p; p += (nbytes + 255) & ~(size_t)255; return r; };

  int*   counts = (int*)  alloc((size_t)N*4);
  int*   start  = (int*)  alloc((size_t)(N+1)*4);
  int*   bsum   = (int*)  alloc(4096);
  int*   rank   = (int*)  alloc((size_t)E*4);
  u32*   rec    = (u32*)  alloc((size_t)E*RW2*4);
  float* U      = (float*)alloc((size_t)N*256);
  float* dinv   = (float*)alloc((size_t)N*256);
  u16*   xlin   = (u16*)  alloc((size_t)N*128);
  u16*   V      = (u16*)  alloc((size_t)N*128);
  u16*   wimg   = (u16*)  alloc((size_t)(2048 + 64*ST)*2);
  u16*   wiimg  = (u16*)  alloc((size_t)8192*2);
  u16*   wlimg  = (u16*)  alloc((size_t)3*8192*2);

  int gE   = (E + 255) / 256;
  int gA   = (E + EPB - 1) / EPB;
  int nb1  = (N + 1023) / 1024;
  int gN64 = (N + 63) / 64;
  int gNH  = (N*64 + 255) / 256;

  hipMemsetAsync(counts, 0, (size_t)N*4, stream);
  hipMemsetAsync(U, 0, (size_t)N*256, stream);

  prep_k <<<96, 256, 0, stream>>>(W1, W2, Wi, Wl, wimg, wiimg, wlimg);
  histr_k<<<gE, 256, 0, stream>>>(col, counts, rank, E);
  scan1_k<<<nb1, 1024, 0, stream>>>(counts, start, bsum, N);
  scan2_k<<<1, 1024, 0, stream>>>(bsum, nb1, start, N, E);
  scan3_k<<<nb1, 1024, 0, stream>>>(start, bsum, N);
  build2_k<<<gE, 256, 0, stream>>>(rank, start, row, col, ea, rec, E);

  agg_k<0><<<gA, 256, 0, stream>>>(rec, wimg, V, U, E);   // degree
  degfin_k<<<gNH, 256, 0, stream>>>(U, dinv, N*64);
  xlin_k  <<<gN64, 256, 0, stream>>>(x, wiimg, bi, wconv, dinv, xlin, V, N);

  agg_k<1><<<gA, 256, 0, stream>>>(rec, wimg, V, U, E);
  epi_k   <<<gN64, 256, 0, stream>>>(xlin, dinv, U, V, wlimg + 0*8192, bconv +   0, wconv +  64, Wo, out, N, 0);
  agg_k<1><<<gA, 256, 0, stream>>>(rec, wimg, V, U, E);
  epi_k   <<<gN64, 256, 0, stream>>>(xlin, dinv, U, V, wlimg + 1*8192, bconv +  64, wconv + 128, Wo, out, N, 0);
  agg_k<1><<<gA, 256, 0, stream>>>(rec, wimg, V, U, E);
  epi_k   <<<gN64, 256, 0, stream>>>(xlin, dinv, U, V, wlimg + 2*8192, bconv + 128, wconv      , Wo, out, N, 1);
}

// Round 9
// 620.118 us; speedup vs baseline: 1.3036x; 1.0765x over previous
//
#include <hip/hip_runtime.h>

using u16 = unsigned short;
using u32 = unsigned int;

typedef __bf16 v8bf __attribute__((ext_vector_type(8)));
typedef float  v4f  __attribute__((ext_vector_type(4)));

#define ST  68    // u16 stride for agg stage rows (34 dwords: odd -> conflict-free columns)
#define STK 132   // u16 stride for 128-wide bf16 LDS rows
#define EPB 256   // edges per block in agg_k (8 waves x 32 edges)
#define T2S 34    // u16 stride of transposed ew tile rows (17 dwords, odd -> conflict-free)
#define RW2 8     // record width in u32: [0..3]=ea bf16x8, [4]=src, [5]=tgt, [6..7]=pad (32B aligned)

// 1-instruction RNE f32->bf16 (identical rounding to manual round-to-nearest-even)
__device__ __forceinline__ u32 cvtpk(float lo, float hi){
  u32 r; asm("v_cvt_pk_bf16_f32 %0, %1, %2" : "=v"(r) : "v"(lo), "v"(hi)); return r;
}
__device__ __forceinline__ u16 f2b(float f){ return (u16)cvtpk(f, f); }
__device__ __forceinline__ float b2f(u16 b){
  u32 u = ((u32)b) << 16;
  return __builtin_bit_cast(float, u);
}

union bfu { v8bf v; u16 s[8]; u32 w[4]; };

__device__ __forceinline__ v8bf zero8(){
  bfu u;
  #pragma unroll
  for (int i = 0; i < 4; i++) u.w[i] = 0;
  return u.v;
}

// ---------------- one-time weight prep: bf16 images, pre-strided / identity-folded ----------------
__global__ __launch_bounds__(256) void prep_k(const float* __restrict__ W1, const float* __restrict__ W2,
                                              const float* __restrict__ Wi, const float* __restrict__ Wl,
                                              u16* __restrict__ wimg, u16* __restrict__ wiimg,
                                              u16* __restrict__ wlimg){
  int i = blockIdx.x*256 + threadIdx.x;
  if (i < 2048){ int r = i >> 5, k = i & 31; wimg[i] = (k < 8) ? f2b(W1[r*8+k]) : (u16)0; }
  if (i < 64*ST){ int o = i / ST, c = i % ST; wimg[2048+i] = (c < 64) ? f2b(W2[o*64+c]) : (u16)0; }
  if (i < 8192) wiimg[i] = f2b(Wi[i]);
  if (i < 3*8192){
    int oc = i & 8191, o = oc >> 7, c = oc & 127;
    wlimg[i] = f2b(Wl[i] + ((c == o) ? 1.f : 0.f));
  }
}

// ---------------- counting sort by target ----------------

// hist + rank in one pass: the atomic's return value IS the within-bucket rank.
__global__ __launch_bounds__(256) void histr_k(const int* __restrict__ col, int* __restrict__ counts,
                                               int* __restrict__ rank, int E){
  int e = blockIdx.x*256 + threadIdx.x;
  if (e < E) rank[e] = atomicAdd(&counts[col[e]], 1);
}

__global__ __launch_bounds__(1024) void scan1_k(const int* __restrict__ counts, int* __restrict__ start,
                                                int* __restrict__ bsum, int N){
  __shared__ int s[1024];
  int tid = threadIdx.x;
  int i = blockIdx.x*1024 + tid;
  int v = (i < N) ? counts[i] : 0;
  s[tid] = v; __syncthreads();
  for (int off = 1; off < 1024; off <<= 1){
    int t = (tid >= off) ? s[tid-off] : 0;
    __syncthreads();
    s[tid] += t;
    __syncthreads();
  }
  if (i < N) start[i] = s[tid] - v;
  if (tid == 1023) bsum[blockIdx.x] = s[1023];
}

__global__ __launch_bounds__(1024) void scan2_k(int* __restrict__ bsum, int nb, int* __restrict__ start,
                                                int N, int E){
  __shared__ int s[1024];
  int tid = threadIdx.x;
  int v = (tid < nb) ? bsum[tid] : 0;
  s[tid] = v; __syncthreads();
  for (int off = 1; off < 1024; off <<= 1){
    int t = (tid >= off) ? s[tid-off] : 0;
    __syncthreads();
    s[tid] += t;
    __syncthreads();
  }
  if (tid < nb) bsum[tid] = s[tid] - v;
  if (tid == 0) start[N] = E;
}

__global__ __launch_bounds__(1024) void scan3_k(int* __restrict__ start, const int* __restrict__ bsum, int N){
  int i = blockIdx.x*1024 + threadIdx.x;
  if (i < N) start[i] += bsum[blockIdx.x];
}

// minimal-scatter build: all reads coalesced at e; one hot gather (start[col]);
// ONE 32B-aligned record store per edge = exactly one random line-touch, no atomics.
__global__ __launch_bounds__(256) void build2_k(const int* __restrict__ rank, const int* __restrict__ start,
                                                const int* __restrict__ row, const int* __restrict__ col,
                                                const float* __restrict__ ea, u32* __restrict__ rec, int E){
  int e = blockIdx.x*256 + threadIdx.x;
  if (e < E){
    int c = col[e];
    int p = start[c] + rank[e];
    const float4* eap = (const float4*)(ea + (size_t)e*8);
    float4 a0 = eap[0], a1 = eap[1];
    int4* r4 = (int4*)(rec + (size_t)p*RW2);
    r4[0] = make_int4((int)cvtpk(a0.x, a0.y), (int)cvtpk(a0.z, a0.w),
                      (int)cvtpk(a1.x, a1.y), (int)cvtpk(a1.z, a1.w));
    r4[1] = make_int4(row[e], c, 0, 0);
  }
}

// ---------------- fused edge-MLP (both layers MFMA) + segmented aggregation ----------------
// 8 waves/block, 32 edges/wave. layer2 computes ew TRANSPOSED (D[ch][edge]).

template<int MODE>   // 0: degree (xv=1)   1: layer (gather V bf16)
__global__ __launch_bounds__(512) void agg_k(const u32* __restrict__ rec, const u16* __restrict__ wimg,
                                             const u16* __restrict__ V, float* __restrict__ U, int E){
  __shared__ __align__(16) u16 stage[EPB*ST];   // ea -> t1 -> (overlay) t2 [64ch][T2S] per wave
  __shared__ __align__(16) u16 w2s[64*ST];
  __shared__ __align__(16) u16 w1s[64*32];
  __shared__ int sl[EPB], tl[EPB];
  int tid = threadIdx.x;
  int j0 = blockIdx.x*EPB;

  if (tid < EPB){
    int j = j0 + tid;
    int4 a = make_int4(0,0,0,0), b = make_int4(0,0,0,0);
    if (j < E){
      const int4* r4 = (const int4*)(rec + (size_t)j*RW2);
      a = r4[0]; b = r4[1];
    }
    sl[tid] = b.x;
    tl[tid] = b.y;
    *(int2*)&stage[tid*ST]     = make_int2(a.x, a.y);
    *(int2*)&stage[tid*ST + 4] = make_int2(a.z, a.w);
  }
  {
    // stage pre-converted weight images: plain vector copies, no converts.
    // w1s = 2048 u16 = 256 uint4; w2s = 4352 u16 = 544 uint4 (uint4 = 8 u16).
    const uint4* src = (const uint4*)wimg;
    uint4* d1 = (uint4*)w1s;
    uint4* d2 = (uint4*)w2s;
    if (tid < 256) d1[tid] = src[tid];
    for (int i = tid; i < 544; i += 512) d2[i] = src[256 + i];
  }
  __syncthreads();

  int w = tid >> 6, lane = tid & 63;
  int m16 = lane & 15, quad = lane >> 4;
  int base = w*32;

  // ---- layer 1 via MFMA (K padded 8->32; quads 1-3 zero), D[edge][ch] -> t1 in stage ----
  v8bf af1[2];
  #pragma unroll
  for (int mi = 0; mi < 2; mi++){
    af1[mi] = zero8();
    if (quad == 0){
      int rr = base + mi*16 + m16;
      int2 p0 = *(const int2*)&stage[rr*ST];
      int2 p1 = *(const int2*)&stage[rr*ST + 4];
      bfu u; u.w[0] = (u32)p0.x; u.w[1] = (u32)p0.y; u.w[2] = (u32)p1.x; u.w[3] = (u32)p1.y;
      af1[mi] = u.v;
    }
  }
  v4f acc1[2][4];
  #pragma unroll
  for (int mi = 0; mi < 2; mi++)
    #pragma unroll
    for (int ni = 0; ni < 4; ni++) acc1[mi][ni] = (v4f){0.f,0.f,0.f,0.f};
  #pragma unroll
  for (int ni = 0; ni < 4; ni++){
    v8bf bf = *(const v8bf*)&w1s[(ni*16 + m16)*32 + quad*8];
    #pragma unroll
    for (int mi = 0; mi < 2; mi++)
      acc1[mi][ni] = __builtin_amdgcn_mfma_f32_16x16x32_bf16(af1[mi], bf, acc1[mi][ni], 0, 0, 0);
  }
  #pragma unroll
  for (int mi = 0; mi < 2; mi++)
    #pragma unroll
    for (int ni = 0; ni < 4; ni++)
      #pragma unroll
      for (int r = 0; r < 4; r++)
        stage[(base + mi*16 + quad*4 + r)*ST + ni*16 + m16] = f2b(fmaxf(acc1[mi][ni][r], 0.f));

  // ---- layer 2 swapped: D[ch][edge] = W2 x t1^T ----
  // B-frags (t1 rows, contiguous) read BEFORE the t2 overlay writes the same region.
  v8bf bfr[2][2];
  #pragma unroll
  for (int ni = 0; ni < 2; ni++)
    #pragma unroll
    for (int ks = 0; ks < 2; ks++)
      bfr[ni][ks] = *(const v8bf*)&stage[(base + ni*16 + m16)*ST + ks*32 + quad*8];
  v4f acc2[4][2];
  #pragma unroll
  for (int mi = 0; mi < 4; mi++)
    #pragma unroll
    for (int ni = 0; ni < 2; ni++) acc2[mi][ni] = (v4f){0.f,0.f,0.f,0.f};
  #pragma unroll
  for (int ks = 0; ks < 2; ks++)
    #pragma unroll
    for (int mi = 0; mi < 4; mi++){
      v8bf afr = *(const v8bf*)&w2s[(mi*16 + m16)*ST + ks*32 + quad*8];
      #pragma unroll
      for (int ni = 0; ni < 2; ni++)
        acc2[mi][ni] = __builtin_amdgcn_mfma_f32_16x16x32_bf16(afr, bfr[ni][ks], acc2[mi][ni], 0, 0, 0);
    }
  // t2 tile overlays this wave's stage region: [64 ch][T2S] u16 at offset base*ST (2176 u16 exactly)
  int t2b = base*ST;
  #pragma unroll
  for (int mi = 0; mi < 4; mi++)
    #pragma unroll
    for (int ni = 0; ni < 2; ni++)
      #pragma unroll
      for (int r = 0; r < 4; r++)
        stage[t2b + (mi*16 + quad*4 + r)*T2S + ni*16 + m16] = f2b(fmaxf(acc2[mi][ni][r], 0.f));

  // ---- segmented scan over this wave's 32 sorted edges; lane = channel ----
  int lim = E - (j0 + base); if (lim > 32) lim = 32;
  const u32* t2w = (const u32*)&stage[t2b + lane*T2S];
  if (lim == 32){
    int tv = tl[base + (lane & 31)];
    int sv = sl[base + (lane & 31)];
    int tvp = __shfl_up(tv, 1, 32);
    unsigned long long bal = __ballot((lane & 31) != 0 && tv != tvp);
    // pin the (wave-uniform) segment mask to an SGPR so per-q tests are scalar
    u32 m = (u32)__builtin_amdgcn_readfirstlane((int)(u32)bal);
    u32 ew[16];
    #pragma unroll
    for (int i = 0; i < 16; i++) ew[i] = t2w[i];
    // prefetch all 32 gathers upfront: deep VMEM pipeline
    float xv[32];
    #pragma unroll
    for (int q = 0; q < 32; q++){
      if (MODE){
        int src = __builtin_amdgcn_readlane(sv, q);
        xv[q] = b2f(V[(size_t)src*64 + lane]);
      } else xv[q] = 1.f;
    }
    float s = 0.f;
    int cur = __builtin_amdgcn_readlane(tv, 0);
    #pragma unroll
    for (int q = 0; q < 32; q++){
      if (m & (1u << q)){
        atomicAdd(&U[(size_t)cur*64 + lane], s); s = 0.f;
        cur = __builtin_amdgcn_readlane(tv, q);
      }
      u32 wb = ew[q >> 1];
      u32 bits = (q & 1) ? (wb & 0xffff0000u) : (wb << 16);
      s += __builtin_bit_cast(float, bits) * xv[q];
    }
    atomicAdd(&U[(size_t)cur*64 + lane], s);
  } else if (lim > 0){
    float s = 0.f;
    int cur = tl[base];
    for (int q = 0; q < lim; q++){
      float wv = b2f(stage[t2b + lane*T2S + q]);
      float xvv = MODE ? b2f(V[(size_t)sl[base+q]*64 + lane]) : 1.f;
      int t = tl[base+q];
      if (t != cur){ atomicAdd(&U[(size_t)cur*64 + lane], s); s = 0.f; cur = t; }
      s += wv*xvv;
    }
    atomicAdd(&U[(size_t)cur*64 + lane], s);
  }
}

__global__ __launch_bounds__(256) void degfin_k(float* __restrict__ U, float* __restrict__ dinv, int NH){
  int i = blockIdx.x*256 + threadIdx.x;
  if (i < NH){
    dinv[i] = rsqrtf(1.f + U[i]);
    U[i] = 0.f;
  }
}

// ---------------- xlin via MFMA: 64 nodes/block; xlin stored bf16 ----------------

__global__ __launch_bounds__(256) void xlin_k(const float* __restrict__ x, const u16* __restrict__ wiimg,
                                              const float* __restrict__ bi, const float* __restrict__ wconv0,
                                              const float* __restrict__ dinv,
                                              u16* __restrict__ xlin, u16* __restrict__ V, int N){
  __shared__ __align__(16) u16 wb[64*STK];   // Wi bf16 [o][k]
  __shared__ __align__(16) u16 as[64*STK];   // x  bf16 [node][k]
  int tid = threadIdx.x;
  // wb copy: 8192 u16 = 2048 uint2 (uint2 = 4 u16; rows 8B-aligned at stride STK)
  for (int i = tid; i < 2048; i += 256){ int o = i >> 5, c = i & 31; *(uint2*)&wb[o*STK + c*4] = ((const uint2*)wiimg)[i]; }
  int nb0 = blockIdx.x*64;
  // x staging: pair-convert via cvt_pk, store u32
  for (int i = tid; i < 4096; i += 256){
    int nn = i >> 6, k2 = i & 63; int n = nb0 + nn;
    u32 v = 0;
    if (n < N){ float2 xx = *(const float2*)&x[(size_t)n*128 + k2*2]; v = cvtpk(xx.x, xx.y); }
    *(u32*)&as[nn*STK + k2*2] = v;
  }
  __syncthreads();
  int w = tid >> 6, lane = tid & 63;
  int m16 = lane & 15, quad = lane >> 4;
  int wbase = w*16;
  v8bf af[4];
  #pragma unroll
  for (int ks = 0; ks < 4; ks++) af[ks] = *(const v8bf*)&as[(wbase+m16)*STK + ks*32 + quad*8];
  v4f acc[4];
  #pragma unroll
  for (int ni = 0; ni < 4; ni++) acc[ni] = (v4f){0.f,0.f,0.f,0.f};
  #pragma unroll
  for (int ks = 0; ks < 4; ks++){
    #pragma unroll
    for (int ni = 0; ni < 4; ni++){
      v8bf bf = *(const v8bf*)&wb[(ni*16+m16)*STK + ks*32 + quad*8];
      acc[ni] = __builtin_amdgcn_mfma_f32_16x16x32_bf16(af[ks], bf, acc[ni], 0, 0, 0);
    }
  }
  #pragma unroll
  for (int ni = 0; ni < 4; ni++){
    int c = ni*16 + m16;
    float wc = wconv0[c], bc = bi[c];
    #pragma unroll
    for (int r = 0; r < 4; r++){
      int n = nb0 + wbase + quad*4 + r;
      if (n < N){
        float val = acc[ni][r] + bc;
        size_t idx = (size_t)n*64 + c;
        xlin[idx] = f2b(val);
        V[idx] = f2b(fmaxf(val, 0.f) * wc * dinv[idx]);
      }
    }
  }
}

// ---------------- epilogue via MFMA: residual folded as identity in Wl (prep'd) ----------------

__global__ __launch_bounds__(256) void epi_k(const u16* __restrict__ xlin, const float* __restrict__ dinv,
                                             float* __restrict__ U, u16* __restrict__ V,
                                             const u16* __restrict__ wlimg, const float* __restrict__ bconv,
                                             const float* __restrict__ wconv_next, const float* __restrict__ Wo,
                                             float* __restrict__ out, int N, int last){
  __shared__ __align__(16) u16 wb[64*STK];   // (Wl + [I|0]) bf16 [o][c]
  __shared__ __align__(16) u16 an[64*STK];   // concat(x_, g) bf16 [node][c]
  int tid = threadIdx.x;
  for (int i = tid; i < 2048; i += 256){ int o = i >> 5, c = i & 31; *(uint2*)&wb[o*STK + c*4] = ((const uint2*)wlimg)[i]; }
  int nb0 = blockIdx.x*64;
  for (int i = tid; i < 4096; i += 256){
    int nn = i >> 6, c = i & 63; int n = nb0 + nn;
    u16 xb = 0, gb = 0;
    if (n < N){
      size_t idx = (size_t)n*64 + c;
      xb = xlin[idx];
      float g = dinv[idx]*(b2f(V[idx]) + U[idx]) + bconv[c];
      gb = f2b(g);
      if (!last) U[idx] = 0.f;
    }
    an[nn*STK + c] = xb;
    an[nn*STK + 64 + c] = gb;
  }
  __syncthreads();
  int w = tid >> 6, lane = tid & 63;
  int m16 = lane & 15, quad = lane >> 4;
  int wbase = w*16;
  v8bf af[4];
  #pragma unroll
  for (int ks = 0; ks < 4; ks++) af[ks] = *(const v8bf*)&an[(wbase+m16)*STK + ks*32 + quad*8];
  v4f acc[4];
  #pragma unroll
  for (int ni = 0; ni < 4; ni++) acc[ni] = (v4f){0.f,0.f,0.f,0.f};
  #pragma unroll
  for (int ks = 0; ks < 4; ks++){
    #pragma unroll
    for (int ni = 0; ni < 4; ni++){
      v8bf bf = *(const v8bf*)&wb[(ni*16+m16)*STK + ks*32 + quad*8];
      acc[ni] = __builtin_amdgcn_mfma_f32_16x16x32_bf16(af[ks], bf, acc[ni], 0, 0, 0);
    }
  }
  if (!last){
    #pragma unroll
    for (int ni = 0; ni < 4; ni++){
      int c = ni*16 + m16;
      float wc = wconv_next[c];
      #pragma unroll
      for (int r = 0; r < 4; r++){
        int n = nb0 + wbase + quad*4 + r;
        if (n < N){
          size_t idx = (size_t)n*64 + c;
          V[idx] = f2b(fmaxf(acc[ni][r], 0.f) * wc * dinv[idx]);
        }
      }
    }
  } else {
    float part[4];
    #pragma unroll
    for (int r = 0; r < 4; r++){
      float p = 0.f;
      int rowl = wbase + quad*4 + r;
      #pragma unroll
      for (int ni = 0; ni < 4; ni++){
        int c = ni*16 + m16;
        float xl = b2f(an[rowl*STK + c]);
        float hr = fmaxf(acc[ni][r], 0.f);
        p += xl*Wo[c] + hr*Wo[64 + c];
      }
      part[r] = p;
    }
    #pragma unroll
    for (int off = 1; off < 16; off <<= 1)
      #pragma unroll
      for (int r = 0; r < 4; r++) part[r] += __shfl_xor(part[r], off, 64);
    if (m16 == 0){
      #pragma unroll
      for (int r = 0; r < 4; r++){
        int n = nb0 + wbase + quad*4 + r;
        if (n < N) out[n] = part[r];
      }
    }
  }
}

extern "C" void kernel_launch(void* const* d_in, const int* in_sizes, int n_in,
                              void* d_out, int out_size, void* d_ws, size_t ws_size,
                              hipStream_t stream){
  const float* x     = (const float*)d_in[0];
  const int*   ei    = (const int*)  d_in[1];
  const float* ea    = (const float*)d_in[2];
  const float* W1    = (const float*)d_in[3];
  const float* W2    = (const float*)d_in[4];
  const float* Wi    = (const float*)d_in[5];
  const float* bi    = (const float*)d_in[6];
  const float* wconv = (const float*)d_in[7];
  const float* bconv = (const float*)d_in[8];
  const float* Wl    = (const float*)d_in[9];
  const float* Wo    = (const float*)d_in[10];
  float* out = (float*)d_out;

  int N = in_sizes[0] / 128;
  int E = in_sizes[2] / 8;
  const int* row = ei;
  const int* col = ei + E;

  char* p = (char*)d_ws;
  auto alloc = [&](size_t nbytes){ char* r = p; p += (nbytes + 255) & ~(size_t)255; return r; };

  int*   counts = (int*)  alloc((size_t)N*4);
  int*   start  = (int*)  alloc((size_t)(N+1)*4);
  int*   bsum   = (int*)  alloc(4096);
  int*   rank   = (int*)  alloc((size_t)E*4);
  u32*   rec    = (u32*)  alloc((size_t)E*RW2*4);
  float* U      = (float*)alloc((size_t)N*256);
  float* dinv   = (float*)alloc((size_t)N*256);
  u16*   xlin   = (u16*)  alloc((size_t)N*128);
  u16*   V      = (u16*)  alloc((size_t)N*128);
  u16*   wimg   = (u16*)  alloc((size_t)(2048 + 64*ST)*2);
  u16*   wiimg  = (u16*)  alloc((size_t)8192*2);
  u16*   wlimg  = (u16*)  alloc((size_t)3*8192*2);

  int gE   = (E + 255) / 256;
  int gA   = (E + EPB - 1) / EPB;
  int nb1  = (N + 1023) / 1024;
  int gN64 = (N + 63) / 64;
  int gNH  = (N*64 + 255) / 256;

  hipMemsetAsync(counts, 0, (size_t)N*4, stream);
  hipMemsetAsync(U, 0, (size_t)N*256, stream);

  prep_k <<<96, 256, 0, stream>>>(W1, W2, Wi, Wl, wimg, wiimg, wlimg);
  histr_k<<<gE, 256, 0, stream>>>(col, counts, rank, E);
  scan1_k<<<nb1, 1024, 0, stream>>>(counts, start, bsum, N);
  scan2_k<<<1, 1024, 0, stream>>>(bsum, nb1, start, N, E);
  scan3_k<<<nb1, 1024, 0, stream>>>(start, bsum, N);
  build2_k<<<gE, 256, 0, stream>>>(rank, start, row, col, ea, rec, E);

  agg_k<0><<<gA, 512, 0, stream>>>(rec, wimg, V, U, E);   // degree
  degfin_k<<<gNH, 256, 0, stream>>>(U, dinv, N*64);
  xlin_k  <<<gN64, 256, 0, stream>>>(x, wiimg, bi, wconv, dinv, xlin, V, N);

  agg_k<1><<<gA, 512, 0, stream>>>(rec, wimg, V, U, E);
  epi_k   <<<gN64, 256, 0, stream>>>(xlin, dinv, U, V, wlimg + 0*8192, bconv +   0, wconv +  64, Wo, out, N, 0);
  agg_k<1><<<gA, 512, 0, stream>>>(rec, wimg, V, U, E);
  epi_k   <<<gN64, 256, 0, stream>>>(xlin, dinv, U, V, wlimg + 1*8192, bconv +  64, wconv + 128, Wo, out, N, 0);
  agg_k<1><<<gA, 512, 0, stream>>>(rec, wimg, V, U, E);
  epi_k   <<<gN64, 256, 0, stream>>>(xlin, dinv, U, V, wlimg + 2*8192, bconv + 128, wconv      , Wo, out, N, 1);
}

// Round 10
// 611.786 us; speedup vs baseline: 1.3214x; 1.0136x over previous
//
#include <hip/hip_runtime.h>

using u16 = unsigned short;
using u32 = unsigned int;

typedef __bf16 v8bf __attribute__((ext_vector_type(8)));
typedef float  v4f  __attribute__((ext_vector_type(4)));

#define ST  68    // u16 stride for agg stage rows (34 dwords: odd -> conflict-free columns)
#define STK 132   // u16 stride for 128-wide bf16 LDS rows
#define EPB 256   // edges per block in agg_k (8 waves x 32 edges)
#define T2S 34    // u16 stride of transposed ew tile rows (17 dwords, odd -> conflict-free)
#define RW2 8     // record width in u32: [0..3]=ea bf16x8, [4]=src, [5]=tgt, [6..7]=pad (32B aligned)

// 1-instruction RNE f32->bf16 (identical rounding to manual round-to-nearest-even)
__device__ __forceinline__ u32 cvtpk(float lo, float hi){
  u32 r; asm("v_cvt_pk_bf16_f32 %0, %1, %2" : "=v"(r) : "v"(lo), "v"(hi)); return r;
}
__device__ __forceinline__ u16 f2b(float f){ return (u16)cvtpk(f, f); }
__device__ __forceinline__ float b2f(u16 b){
  u32 u = ((u32)b) << 16;
  return __builtin_bit_cast(float, u);
}

union bfu { v8bf v; u16 s[8]; u32 w[4]; };

__device__ __forceinline__ v8bf zero8(){
  bfu u;
  #pragma unroll
  for (int i = 0; i < 4; i++) u.w[i] = 0;
  return u.v;
}

// ---------------- fused prologue: weight prep + zero counts + zero U (absorbs both memsets) ----------------
__global__ __launch_bounds__(256) void prep0_k(const float* __restrict__ W1, const float* __restrict__ W2,
                                               const float* __restrict__ Wi, const float* __restrict__ Wl,
                                               u16* __restrict__ wimg, u16* __restrict__ wiimg,
                                               u16* __restrict__ wlimg, int* __restrict__ counts,
                                               float4* __restrict__ U4, int N, int nU4){
  int gs = gridDim.x*256;
  int t0 = blockIdx.x*256 + threadIdx.x;
  for (int i = t0; i < 3*8192; i += gs){
    if (i < 2048){ int r = i >> 5, k = i & 31; wimg[i] = (k < 8) ? f2b(W1[r*8+k]) : (u16)0; }
    if (i < 64*ST){ int o = i / ST, c = i % ST; wimg[2048+i] = (c < 64) ? f2b(W2[o*64+c]) : (u16)0; }
    if (i < 8192) wiimg[i] = f2b(Wi[i]);
    { int oc = i & 8191, o = oc >> 7, c = oc & 127; wlimg[i] = f2b(Wl[i] + ((c == o) ? 1.f : 0.f)); }
  }
  for (int i = t0; i < N; i += gs) counts[i] = 0;
  for (int i = t0; i < nU4; i += gs) U4[i] = make_float4(0.f, 0.f, 0.f, 0.f);
}

// ---------------- counting sort by target ----------------

// hist + rank: the atomic's return value IS the within-bucket rank. 4 edges/thread for atomic MLP.
__global__ __launch_bounds__(256) void histr_k(const int* __restrict__ col, int* __restrict__ counts,
                                               int* __restrict__ rank, int E){
  int e0 = (blockIdx.x*256 + threadIdx.x)*4;
  if (e0 + 3 < E){
    int4 c4 = *(const int4*)(col + e0);
    int r0 = atomicAdd(&counts[c4.x], 1);
    int r1 = atomicAdd(&counts[c4.y], 1);
    int r2 = atomicAdd(&counts[c4.z], 1);
    int r3 = atomicAdd(&counts[c4.w], 1);
    *(int4*)(rank + e0) = make_int4(r0, r1, r2, r3);
  } else {
    for (int i = 0; i < 4; i++){
      int e = e0 + i; if (e >= E) break;
      rank[e] = atomicAdd(&counts[col[e]], 1);
    }
  }
}

__global__ __launch_bounds__(1024) void scan1_k(const int* __restrict__ counts, int* __restrict__ start,
                                                int* __restrict__ bsum, int N){
  __shared__ int s[1024];
  int tid = threadIdx.x;
  int i = blockIdx.x*1024 + tid;
  int v = (i < N) ? counts[i] : 0;
  s[tid] = v; __syncthreads();
  for (int off = 1; off < 1024; off <<= 1){
    int t = (tid >= off) ? s[tid-off] : 0;
    __syncthreads();
    s[tid] += t;
    __syncthreads();
  }
  if (i < N) start[i] = s[tid] - v;
  if (tid == 1023) bsum[blockIdx.x] = s[1023];
}

// merged scan2+scan3: every block redundantly scans the (<=1024) block sums in LDS, applies its offset.
__global__ __launch_bounds__(1024) void scan23_k(const int* __restrict__ bsum, int nb,
                                                 int* __restrict__ start, int N, int E){
  __shared__ int s[1024];
  __shared__ int myoff;
  int tid = threadIdx.x;
  int v = (tid < nb) ? bsum[tid] : 0;
  s[tid] = v; __syncthreads();
  for (int off = 1; off < 1024; off <<= 1){
    int t = (tid >= off) ? s[tid-off] : 0;
    __syncthreads();
    s[tid] += t;
    __syncthreads();
  }
  if (tid == blockIdx.x) myoff = s[tid] - v;   // exclusive prefix of this block's sum
  __syncthreads();
  int i = blockIdx.x*1024 + tid;
  if (i < N) start[i] += myoff;
  if (blockIdx.x == 0 && tid == 0) start[N] = E;
}

// minimal-scatter build: all reads coalesced at e; one hot gather (start[col]);
// ONE 32B-aligned record store per edge = exactly one random line-touch, no atomics.
__global__ __launch_bounds__(256) void build2_k(const int* __restrict__ rank, const int* __restrict__ start,
                                                const int* __restrict__ row, const int* __restrict__ col,
                                                const float* __restrict__ ea, u32* __restrict__ rec, int E){
  int e = blockIdx.x*256 + threadIdx.x;
  if (e < E){
    int c = col[e];
    int p = start[c] + rank[e];
    const float4* eap = (const float4*)(ea + (size_t)e*8);
    float4 a0 = eap[0], a1 = eap[1];
    int4* r4 = (int4*)(rec + (size_t)p*RW2);
    r4[0] = make_int4((int)cvtpk(a0.x, a0.y), (int)cvtpk(a0.z, a0.w),
                      (int)cvtpk(a1.x, a1.y), (int)cvtpk(a1.z, a1.w));
    r4[1] = make_int4(row[e], c, 0, 0);
  }
}

// ---------------- fused edge-MLP (both layers MFMA) + segmented aggregation ----------------
// 8 waves/block, 32 edges/wave. layer2 computes ew TRANSPOSED (D[ch][edge]).

template<int MODE>   // 0: degree (xv=1)   1: layer (gather V bf16)
__global__ __launch_bounds__(512) void agg_k(const u32* __restrict__ rec, const u16* __restrict__ wimg,
                                             const u16* __restrict__ V, float* __restrict__ U, int E){
  __shared__ __align__(16) u16 stage[EPB*ST];   // ea -> t1 -> (overlay) t2 [64ch][T2S] per wave
  __shared__ __align__(16) u16 w2s[64*ST];
  __shared__ __align__(16) u16 w1s[64*32];
  __shared__ int sl[EPB], tl[EPB];
  int tid = threadIdx.x;
  int j0 = blockIdx.x*EPB;

  if (tid < EPB){
    int j = j0 + tid;
    int4 a = make_int4(0,0,0,0), b = make_int4(0,0,0,0);
    if (j < E){
      const int4* r4 = (const int4*)(rec + (size_t)j*RW2);
      a = r4[0]; b = r4[1];
    }
    sl[tid] = b.x;
    tl[tid] = b.y;
    *(int2*)&stage[tid*ST]     = make_int2(a.x, a.y);
    *(int2*)&stage[tid*ST + 4] = make_int2(a.z, a.w);
  }
  {
    // stage pre-converted weight images: plain vector copies, no converts.
    // w1s = 2048 u16 = 256 uint4; w2s = 4352 u16 = 544 uint4 (uint4 = 8 u16).
    const uint4* src = (const uint4*)wimg;
    uint4* d1 = (uint4*)w1s;
    uint4* d2 = (uint4*)w2s;
    if (tid < 256) d1[tid] = src[tid];
    for (int i = tid; i < 544; i += 512) d2[i] = src[256 + i];
  }
  __syncthreads();

  int w = tid >> 6, lane = tid & 63;
  int m16 = lane & 15, quad = lane >> 4;
  int base = w*32;

  // ---- layer 1 via MFMA (K padded 8->32; quads 1-3 zero), D[edge][ch] -> t1 in stage ----
  v8bf af1[2];
  #pragma unroll
  for (int mi = 0; mi < 2; mi++){
    af1[mi] = zero8();
    if (quad == 0){
      int rr = base + mi*16 + m16;
      int2 p0 = *(const int2*)&stage[rr*ST];
      int2 p1 = *(const int2*)&stage[rr*ST + 4];
      bfu u; u.w[0] = (u32)p0.x; u.w[1] = (u32)p0.y; u.w[2] = (u32)p1.x; u.w[3] = (u32)p1.y;
      af1[mi] = u.v;
    }
  }
  v4f acc1[2][4];
  #pragma unroll
  for (int mi = 0; mi < 2; mi++)
    #pragma unroll
    for (int ni = 0; ni < 4; ni++) acc1[mi][ni] = (v4f){0.f,0.f,0.f,0.f};
  #pragma unroll
  for (int ni = 0; ni < 4; ni++){
    v8bf bf = *(const v8bf*)&w1s[(ni*16 + m16)*32 + quad*8];
    #pragma unroll
    for (int mi = 0; mi < 2; mi++)
      acc1[mi][ni] = __builtin_amdgcn_mfma_f32_16x16x32_bf16(af1[mi], bf, acc1[mi][ni], 0, 0, 0);
  }
  #pragma unroll
  for (int mi = 0; mi < 2; mi++)
    #pragma unroll
    for (int ni = 0; ni < 4; ni++)
      #pragma unroll
      for (int r = 0; r < 4; r++)
        stage[(base + mi*16 + quad*4 + r)*ST + ni*16 + m16] = f2b(fmaxf(acc1[mi][ni][r], 0.f));

  // ---- layer 2 swapped: D[ch][edge] = W2 x t1^T ----
  // B-frags (t1 rows, contiguous) read BEFORE the t2 overlay writes the same region.
  v8bf bfr[2][2];
  #pragma unroll
  for (int ni = 0; ni < 2; ni++)
    #pragma unroll
    for (int ks = 0; ks < 2; ks++)
      bfr[ni][ks] = *(const v8bf*)&stage[(base + ni*16 + m16)*ST + ks*32 + quad*8];
  v4f acc2[4][2];
  #pragma unroll
  for (int mi = 0; mi < 4; mi++)
    #pragma unroll
    for (int ni = 0; ni < 2; ni++) acc2[mi][ni] = (v4f){0.f,0.f,0.f,0.f};
  #pragma unroll
  for (int ks = 0; ks < 2; ks++)
    #pragma unroll
    for (int mi = 0; mi < 4; mi++){
      v8bf afr = *(const v8bf*)&w2s[(mi*16 + m16)*ST + ks*32 + quad*8];
      #pragma unroll
      for (int ni = 0; ni < 2; ni++)
        acc2[mi][ni] = __builtin_amdgcn_mfma_f32_16x16x32_bf16(afr, bfr[ni][ks], acc2[mi][ni], 0, 0, 0);
    }
  // t2 tile overlays this wave's stage region: [64 ch][T2S] u16 at offset base*ST (2176 u16 exactly)
  int t2b = base*ST;
  #pragma unroll
  for (int mi = 0; mi < 4; mi++)
    #pragma unroll
    for (int ni = 0; ni < 2; ni++)
      #pragma unroll
      for (int r = 0; r < 4; r++)
        stage[t2b + (mi*16 + quad*4 + r)*T2S + ni*16 + m16] = f2b(fmaxf(acc2[mi][ni][r], 0.f));

  // ---- segmented scan over this wave's 32 sorted edges; lane = channel ----
  int lim = E - (j0 + base); if (lim > 32) lim = 32;
  const u32* t2w = (const u32*)&stage[t2b + lane*T2S];
  if (lim == 32){
    int tv = tl[base + (lane & 31)];
    int sv = sl[base + (lane & 31)];
    int tvp = __shfl_up(tv, 1, 32);
    unsigned long long bal = __ballot((lane & 31) != 0 && tv != tvp);
    // pin the (wave-uniform) segment mask to an SGPR so per-q tests are scalar
    u32 m = (u32)__builtin_amdgcn_readfirstlane((int)(u32)bal);
    u32 ew[16];
    #pragma unroll
    for (int i = 0; i < 16; i++) ew[i] = t2w[i];
    // prefetch all 32 gathers upfront: deep VMEM pipeline
    float xv[32];
    #pragma unroll
    for (int q = 0; q < 32; q++){
      if (MODE){
        int src = __builtin_amdgcn_readlane(sv, q);
        xv[q] = b2f(V[(size_t)src*64 + lane]);
      } else xv[q] = 1.f;
    }
    float s = 0.f;
    int cur = __builtin_amdgcn_readlane(tv, 0);
    #pragma unroll
    for (int q = 0; q < 32; q++){
      if (m & (1u << q)){
        atomicAdd(&U[(size_t)cur*64 + lane], s); s = 0.f;
        cur = __builtin_amdgcn_readlane(tv, q);
      }
      u32 wb = ew[q >> 1];
      u32 bits = (q & 1) ? (wb & 0xffff0000u) : (wb << 16);
      s += __builtin_bit_cast(float, bits) * xv[q];
    }
    atomicAdd(&U[(size_t)cur*64 + lane], s);
  } else if (lim > 0){
    float s = 0.f;
    int cur = tl[base];
    for (int q = 0; q < lim; q++){
      float wv = b2f(stage[t2b + lane*T2S + q]);
      float xvv = MODE ? b2f(V[(size_t)sl[base+q]*64 + lane]) : 1.f;
      int t = tl[base+q];
      if (t != cur){ atomicAdd(&U[(size_t)cur*64 + lane], s); s = 0.f; cur = t; }
      s += wv*xvv;
    }
    atomicAdd(&U[(size_t)cur*64 + lane], s);
  }
}

// ---------------- xlin via MFMA (64 nodes/block) with degfin folded into the epilogue ----------------

__global__ __launch_bounds__(256) void xlin_k(const float* __restrict__ x, const u16* __restrict__ wiimg,
                                              const float* __restrict__ bi, const float* __restrict__ wconv0,
                                              float* __restrict__ U, float* __restrict__ dinv,
                                              u16* __restrict__ xlin, u16* __restrict__ V, int N){
  __shared__ __align__(16) u16 wb[64*STK];   // Wi bf16 [o][k]
  __shared__ __align__(16) u16 as[64*STK];   // x  bf16 [node][k]
  int tid = threadIdx.x;
  // wb copy: 8192 u16 = 2048 uint2 (uint2 = 4 u16; rows 8B-aligned at stride STK)
  for (int i = tid; i < 2048; i += 256){ int o = i >> 5, c = i & 31; *(uint2*)&wb[o*STK + c*4] = ((const uint2*)wiimg)[i]; }
  int nb0 = blockIdx.x*64;
  // x staging: pair-convert via cvt_pk, store u32
  for (int i = tid; i < 4096; i += 256){
    int nn = i >> 6, k2 = i & 63; int n = nb0 + nn;
    u32 v = 0;
    if (n < N){ float2 xx = *(const float2*)&x[(size_t)n*128 + k2*2]; v = cvtpk(xx.x, xx.y); }
    *(u32*)&as[nn*STK + k2*2] = v;
  }
  __syncthreads();
  int w = tid >> 6, lane = tid & 63;
  int m16 = lane & 15, quad = lane >> 4;
  int wbase = w*16;
  v8bf af[4];
  #pragma unroll
  for (int ks = 0; ks < 4; ks++) af[ks] = *(const v8bf*)&as[(wbase+m16)*STK + ks*32 + quad*8];
  v4f acc[4];
  #pragma unroll
  for (int ni = 0; ni < 4; ni++) acc[ni] = (v4f){0.f,0.f,0.f,0.f};
  #pragma unroll
  for (int ks = 0; ks < 4; ks++){
    #pragma unroll
    for (int ni = 0; ni < 4; ni++){
      v8bf bf = *(const v8bf*)&wb[(ni*16+m16)*STK + ks*32 + quad*8];
      acc[ni] = __builtin_amdgcn_mfma_f32_16x16x32_bf16(af[ks], bf, acc[ni], 0, 0, 0);
    }
  }
  #pragma unroll
  for (int ni = 0; ni < 4; ni++){
    int c = ni*16 + m16;
    float wc = wconv0[c], bc = bi[c];
    #pragma unroll
    for (int r = 0; r < 4; r++){
      int n = nb0 + wbase + quad*4 + r;
      if (n < N){
        float val = acc[ni][r] + bc;
        size_t idx = (size_t)n*64 + c;
        float dv = rsqrtf(1.f + U[idx]);   // degfin folded: U holds degree sums here
        dinv[idx] = dv;
        U[idx] = 0.f;
        xlin[idx] = f2b(val);
        V[idx] = f2b(fmaxf(val, 0.f) * wc * dv);
      }
    }
  }
}

// ---------------- epilogue via MFMA: residual folded as identity in Wl (prep'd) ----------------

__global__ __launch_bounds__(256) void epi_k(const u16* __restrict__ xlin, const float* __restrict__ dinv,
                                             float* __restrict__ U, u16* __restrict__ V,
                                             const u16* __restrict__ wlimg, const float* __restrict__ bconv,
                                             const float* __restrict__ wconv_next, const float* __restrict__ Wo,
                                             float* __restrict__ out, int N, int last){
  __shared__ __align__(16) u16 wb[64*STK];   // (Wl + [I|0]) bf16 [o][c]
  __shared__ __align__(16) u16 an[64*STK];   // concat(x_, g) bf16 [node][c]
  int tid = threadIdx.x;
  for (int i = tid; i < 2048; i += 256){ int o = i >> 5, c = i & 31; *(uint2*)&wb[o*STK + c*4] = ((const uint2*)wlimg)[i]; }
  int nb0 = blockIdx.x*64;
  for (int i = tid; i < 4096; i += 256){
    int nn = i >> 6, c = i & 63; int n = nb0 + nn;
    u16 xb = 0, gb = 0;
    if (n < N){
      size_t idx = (size_t)n*64 + c;
      xb = xlin[idx];
      float g = dinv[idx]*(b2f(V[idx]) + U[idx]) + bconv[c];
      gb = f2b(g);
      if (!last) U[idx] = 0.f;
    }
    an[nn*STK + c] = xb;
    an[nn*STK + 64 + c] = gb;
  }
  __syncthreads();
  int w = tid >> 6, lane = tid & 63;
  int m16 = lane & 15, quad = lane >> 4;
  int wbase = w*16;
  v8bf af[4];
  #pragma unroll
  for (int ks = 0; ks < 4; ks++) af[ks] = *(const v8bf*)&an[(wbase+m16)*STK + ks*32 + quad*8];
  v4f acc[4];
  #pragma unroll
  for (int ni = 0; ni < 4; ni++) acc[ni] = (v4f){0.f,0.f,0.f,0.f};
  #pragma unroll
  for (int ks = 0; ks < 4; ks++){
    #pragma unroll
    for (int ni = 0; ni < 4; ni++){
      v8bf bf = *(const v8bf*)&wb[(ni*16+m16)*STK + ks*32 + quad*8];
      acc[ni] = __builtin_amdgcn_mfma_f32_16x16x32_bf16(af[ks], bf, acc[ni], 0, 0, 0);
    }
  }
  if (!last){
    #pragma unroll
    for (int ni = 0; ni < 4; ni++){
      int c = ni*16 + m16;
      float wc = wconv_next[c];
      #pragma unroll
      for (int r = 0; r < 4; r++){
        int n = nb0 + wbase + quad*4 + r;
        if (n < N){
          size_t idx = (size_t)n*64 + c;
          V[idx] = f2b(fmaxf(acc[ni][r], 0.f) * wc * dinv[idx]);
        }
      }
    }
  } else {
    float part[4];
    #pragma unroll
    for (int r = 0; r < 4; r++){
      float p = 0.f;
      int rowl = wbase + quad*4 + r;
      #pragma unroll
      for (int ni = 0; ni < 4; ni++){
        int c = ni*16 + m16;
        float xl = b2f(an[rowl*STK + c]);
        float hr = fmaxf(acc[ni][r], 0.f);
        p += xl*Wo[c] + hr*Wo[64 + c];
      }
      part[r] = p;
    }
    #pragma unroll
    for (int off = 1; off < 16; off <<= 1)
      #pragma unroll
      for (int r = 0; r < 4; r++) part[r] += __shfl_xor(part[r], off, 64);
    if (m16 == 0){
      #pragma unroll
      for (int r = 0; r < 4; r++){
        int n = nb0 + wbase + quad*4 + r;
        if (n < N) out[n] = part[r];
      }
    }
  }
}

extern "C" void kernel_launch(void* const* d_in, const int* in_sizes, int n_in,
                              void* d_out, int out_size, void* d_ws, size_t ws_size,
                              hipStream_t stream){
  const float* x     = (const float*)d_in[0];
  const int*   ei    = (const int*)  d_in[1];
  const float* ea    = (const float*)d_in[2];
  const float* W1    = (const float*)d_in[3];
  const float* W2    = (const float*)d_in[4];
  const float* Wi    = (const float*)d_in[5];
  const float* bi    = (const float*)d_in[6];
  const float* wconv = (const float*)d_in[7];
  const float* bconv = (const float*)d_in[8];
  const float* Wl    = (const float*)d_in[9];
  const float* Wo    = (const float*)d_in[10];
  float* out = (float*)d_out;

  int N = in_sizes[0] / 128;
  int E = in_sizes[2] / 8;
  const int* row = ei;
  const int* col = ei + E;

  char* p = (char*)d_ws;
  auto alloc = [&](size_t nbytes){ char* r = p; p += (nbytes + 255) & ~(size_t)255; return r; };

  int*   counts = (int*)  alloc((size_t)N*4);
  int*   start  = (int*)  alloc((size_t)(N+1)*4);
  int*   bsum   = (int*)  alloc(4096);
  int*   rank   = (int*)  alloc((size_t)E*4);
  u32*   rec    = (u32*)  alloc((size_t)E*RW2*4);
  float* U      = (float*)alloc((size_t)N*256);
  float* dinv   = (float*)alloc((size_t)N*256);
  u16*   xlin   = (u16*)  alloc((size_t)N*128);
  u16*   V      = (u16*)  alloc((size_t)N*128);
  u16*   wimg   = (u16*)  alloc((size_t)(2048 + 64*ST)*2);
  u16*   wiimg  = (u16*)  alloc((size_t)8192*2);
  u16*   wlimg  = (u16*)  alloc((size_t)3*8192*2);

  int gE   = (E + 255) / 256;
  int gE4  = (E + 1023) / 1024;
  int gA   = (E + EPB - 1) / EPB;
  int nb1  = (N + 1023) / 1024;
  int gN64 = (N + 63) / 64;

  prep0_k<<<2048, 256, 0, stream>>>(W1, W2, Wi, Wl, wimg, wiimg, wlimg, counts, (float4*)U, N, N*16);
  histr_k<<<gE4, 256, 0, stream>>>(col, counts, rank, E);
  scan1_k<<<nb1, 1024, 0, stream>>>(counts, start, bsum, N);
  scan23_k<<<nb1, 1024, 0, stream>>>(bsum, nb1, start, N, E);
  build2_k<<<gE, 256, 0, stream>>>(rank, start, row, col, ea, rec, E);

  agg_k<0><<<gA, 512, 0, stream>>>(rec, wimg, V, U, E);   // degree
  xlin_k  <<<gN64, 256, 0, stream>>>(x, wiimg, bi, wconv, U, dinv, xlin, V, N);   // + degfin folded

  agg_k<1><<<gA, 512, 0, stream>>>(rec, wimg, V, U, E);
  epi_k   <<<gN64, 256, 0, stream>>>(xlin, dinv, U, V, wlimg + 0*8192, bconv +   0, wconv +  64, Wo, out, N, 0);
  agg_k<1><<<gA, 512, 0, stream>>>(rec, wimg, V, U, E);
  epi_k   <<<gN64, 256, 0, stream>>>(xlin, dinv, U, V, wlimg + 1*8192, bconv +  64, wconv + 128, Wo, out, N, 0);
  agg_k<1><<<gA, 512, 0, stream>>>(rec, wimg, V, U, E);
  epi_k   <<<gN64, 256, 0, stream>>>(xlin, dinv, U, V, wlimg + 2*8192, bconv + 128, wconv      , Wo, out, N, 1);
}